// Round 7
// baseline (484.071 us; speedup 1.0000x reference)
//
#include <hip/hip_runtime.h>

typedef unsigned short u16;
typedef __attribute__((ext_vector_type(8))) short bf16x8;   // 8 x bf16 (4 VGPRs)
typedef __attribute__((ext_vector_type(4))) float f32x4;

#define NLEV 5
#define CCH 256
#define KTOT 2304            // 9 taps * 256 ci
#define P_TOT 8525           // sum HW
#define PP_TOT 9165          // sum (H+2)*(W+2)
#define PLS (PP_TOT*64)      // activation plane stride (u16), 4 planes of 64 ci

__constant__ int   c_HW[NLEV]     = {6400, 1600, 400, 100, 25};
__constant__ int   c_W[NLEV]      = {80, 40, 20, 10, 5};    // H == W (square)
__constant__ int   c_off[NLEV]    = {0, 6400, 8000, 8400, 8500};
__constant__ int   c_poff[NLEV]   = {0, 6724, 8488, 8972, 9116};
__constant__ int   c_tls[NLEV+1]  = {0, 50, 65, 71, 73, 74};  // 16x8 tile starts
__constant__ int   c_ntx[NLEV]    = {5, 3, 2, 1, 1};          // tiles across
__constant__ float c_stridef[NLEV]= {8.f, 16.f, 32.f, 64.f, 128.f};

__device__ __forceinline__ u16 f2bf(float f){
  union { float f; unsigned u; } v; v.f = f;
  unsigned r = v.u + 0x7fffu + ((v.u >> 16) & 1u);   // RNE
  return (u16)(r >> 16);
}

// ---------------------------------------------------------------------------
// R7: DECOUPLED 1-WAVE STREAMS. R2-R6 (six K-loop variants) all flat at ~330:
// the shared skeleton (47KB LDS halo dbuf + barriers + vmcnt + 2-wave blocks
// at ~1.5 waves/SIMD) kept the per-titer critical path ~3.5 Kcyc vs the
// ~470cyc MFMA floor (MfmaUtil 8%). Every fix addressed one link; the
// skeleton kept the rest. Key identity: the swizzled LDS halo read equals a
// PLAIN global read of planar X (store/read XORs cancel:
// LDS[hp*64+q*8] == X[pix(hp)*64+q*8]), and the halo working set (23KB/cc,
// reused 3x by dw) is L1/L2-resident. So this version deletes the skeleton:
//   - 1-wave (64-thr) blocks, ZERO LDS, ZERO barriers, ZERO manual waitcnt
//   - A and B both global->register, depth-1 software pipeline at
//     half-titer (sub) granularity: sets {A:6,B:10}x2 = 128 VGPR + acc 64;
//     stage k+1 loads issue while stage k's 48 MFMAs run (~233cyc covers L2)
//   - GN stats: wave shfl-reduce then atomicAdd direct to global
// MFMA order & operand values bit-identical to R6 (stage sub0 then sub1,
// each dh->mt->nt) -> absmax must stay exactly 0.625.
// Stage k (k=0..23): u=k>>1, s=k&1, cc=u/3, dw=u%3.
//   A frag: aln + ((dh*3+dw)*4+cc)*SZ + (s*2+mt)*512
//   B frag: X + cc*PLS + (c_poff+(ty0+n2)*wrow2+tx0+l15+dw)*64 + (s*4+quad)*8
// (B rows n2=0..9 cover all 3 dh taps; out-of-range rows for small levels
// read in-workspace garbage that the nt/gx write guards discard - same
// addresses the old halo staged.)
// MODE 0: towers, grid (1184 = 74p x 8g2 x 2br), bid = (br*8+g2)*74 + p.
// MODE 1: heads,  grid (296 = 74 x 4 jobs): j<3 -> br0 g2=j (co 0..95,
//         m<80); j==3 -> br1 g2=0 (pred m<4 + iou m==4).
// ---------------------------------------------------------------------------
template<int MODE>
__global__ __launch_bounds__(64)
__attribute__((amdgpu_waves_per_eu(2, 2)))
void gemm_conv(
    const u16* __restrict__ Xc, const u16* __restrict__ Xb,
    const u16* __restrict__ Wc, const u16* __restrict__ Wb,
    const float* __restrict__ bc, const float* __restrict__ bb,
    float* __restrict__ Yc, float* __restrict__ Yb,
    float* __restrict__ stats,
    const float* __restrict__ predb, const float* __restrict__ ioub,
    const float* __restrict__ scales, float* __restrict__ out)
{
  const int bid = blockIdx.x;
  const int ptile = bid % 74;
  const int j     = bid / 74;
  const int g2 = (MODE == 0) ? (j & 7) : (j < 3 ? j : 0);
  const int br = (MODE == 0) ? (j >> 3) : (j == 3 ? 1 : 0);

  int lv = 0;
  #pragma unroll
  for (int i = 1; i < NLEV; i++) if (ptile >= c_tls[i]) lv = i;
  const int tidx = ptile - c_tls[lv];
  const int ntx = c_ntx[lv];
  const int ty0 = (tidx / ntx) * 8, tx0 = (tidx - (tidx / ntx) * ntx) * 16;
  const int W = c_W[lv], wrow2 = W + 2;

  const int ln = threadIdx.x & 63;
  const int quad = ln >> 4, l15 = ln & 15;

  const u16* __restrict__ X  = br ? Xb : Xc;   // planar activations
  const u16* __restrict__ WA = br ? Wb : Wc;   // packed weights

  const int SZ = (MODE == 0) ? 16384 : 8192;   // per-stage A u16s
  const u16* aln = WA + (size_t)(g2*2048 + ln*8);
  // per-lane B base: pixel (ty0, tx0+l15) of padded plane, ci-group quad
  const u16* xb0 = X + (size_t)(c_poff[lv] + ty0*wrow2 + tx0 + l15) * 64
                     + quad*8;
  const int brow = wrow2 * 64;                 // B row stride (u16)

  f32x4 acc[2][8];
  #pragma unroll
  for (int i = 0; i < 2; i++)
    #pragma unroll
    for (int jj = 0; jj < 8; jj++) acc[i][jj] = (f32x4){0.f, 0.f, 0.f, 0.f};

  // pipeline register sets (static indexing only)
  bf16x8 aA[6], bA[10], aB[6], bB[10];

  auto ldStage = [&](int k, bf16x8 (&a)[6], bf16x8 (&b)[10]) {
    const int u = k >> 1, s = k & 1;
    const int cc = u / 3, dw = u - cc*3;
    #pragma unroll
    for (int dh = 0; dh < 3; dh++)
      #pragma unroll
      for (int mt = 0; mt < 2; mt++)
        a[dh*2 + mt] = *(const bf16x8*)
            (aln + (size_t)((dh*3 + dw)*4 + cc) * SZ + (s*2 + mt)*512);
    const u16* bp = xb0 + (size_t)cc * PLS + (size_t)dw * 64 + s*32;
    #pragma unroll
    for (int n2 = 0; n2 < 10; n2++)
      b[n2] = *(const bf16x8*)(bp + (size_t)n2 * brow);
  };
  auto cmpStage = [&](bf16x8 (&a)[6], bf16x8 (&b)[10]) {
    #pragma unroll
    for (int dh = 0; dh < 3; dh++)
      #pragma unroll
      for (int mt = 0; mt < 2; mt++)
        #pragma unroll
        for (int nt = 0; nt < 8; nt++)
          acc[mt][nt] = __builtin_amdgcn_mfma_f32_16x16x32_bf16(
              a[dh*2 + mt], b[nt + dh], acc[mt][nt], 0, 0, 0);
  };

  // ---- K-loop: 24 half-titer stages, depth-1 register pipeline ----
  ldStage(0, aA, bA);
  #pragma unroll 1
  for (int k = 0; k < 24; k += 2) {
    if (k + 1 < 24) ldStage(k + 1, aB, bB);
    cmpStage(aA, bA);
    if (k + 2 < 24) ldStage(k + 2, aA, bA);
    cmpStage(aB, bB);
  }

  const int gx = tx0 + l15;
  if (MODE == 0) {
    const float* __restrict__ bias = br ? bb : bc;
    float* __restrict__ Y = br ? Yb : Yc;
    #pragma unroll
    for (int mt = 0; mt < 2; mt++) {
      const int mrow = g2*32 + mt*16 + quad*4;          // 0..255 global co
      const f32x4 bv = *(const f32x4*)&bias[mrow];
      float s = 0.f, sq = 0.f;
      #pragma unroll
      for (int nt = 0; nt < 8; nt++) {
        const int gy = ty0 + nt;
        f32x4 v = acc[mt][nt] + bv;
        if (gy < W && gx < W) {
          const size_t n = (size_t)(c_off[lv] + gy*W + gx);
          *(f32x4*)&Y[n*CCH + mrow] = v;
          #pragma unroll
          for (int r = 0; r < 4; r++) { s += v[r]; sq += v[r]*v[r]; }
        }
      }
      #pragma unroll
      for (int o = 1; o < 16; o <<= 1) { s += __shfl_xor(s, o); sq += __shfl_xor(sq, o); }
      if (l15 == 0) {
        const int G = g2*4 + mt*2 + (quad >> 1);        // global 8-ch group
        atomicAdd(&stats[((br*NLEV + lv)*32 + G)*2 + 0], s);
        atomicAdd(&stats[((br*NLEV + lv)*32 + G)*2 + 1], sq);
      }
    }
  } else {
    const float scl = scales[lv];
    const float stf = c_stridef[lv];
    #pragma unroll
    for (int mt = 0; mt < 2; mt++) {
      const int mr0 = g2*32 + mt*16 + quad*4;
      if (mr0 >= 85) continue;
      #pragma unroll
      for (int nt = 0; nt < 8; nt++) {
        const int gy = ty0 + nt;
        if (gy >= W || gx >= W) continue;
        const size_t n = (size_t)(c_off[lv] + gy*W + gx);
        const f32x4 v = acc[mt][nt];
        #pragma unroll
        for (int r = 0; r < 4; r++) {
          const int m = mr0 + r;
          if (br == 0) {
            if (m < 80) out[n*85 + m] = v[r] + bc[m];          // logits
          } else {
            if (m < 4) {
              const float t = (v[r] + predb[m]) * scl;         // Scale module
              out[n*85 + 80 + m] = fmaxf(t, 0.f) * stf;        // relu * stride
            } else if (m == 4) {
              out[n*85 + 84] = v[r] + ioub[0];                 // iou
            }
          }
        }
      }
    }
  }
}

// GN finalize + affine + ReLU + bf16 cast into PLANAR padded layout.
// Y already includes conv bias.
__global__ __launch_bounds__(256) void gn_relu(
    const float* __restrict__ Yc, const float* __restrict__ Yb,
    const float* __restrict__ stats,
    const float* __restrict__ gwc, const float* __restrict__ gbc,
    const float* __restrict__ gwb, const float* __restrict__ gbb,
    u16* __restrict__ Xc, u16* __restrict__ Xb)
{
  const int t = blockIdx.x * 256 + threadIdx.x;
  if (t >= 2 * P_TOT * 32) return;
  const int br = t / (P_TOT * 32);
  const int r  = t - br * (P_TOT * 32);
  const int pg = r >> 5;
  const int c0 = (r & 31) << 3;
  int lv = 0;
  #pragma unroll
  for (int i = 1; i < NLEV; i++) if (pg >= c_off[i]) lv = i;
  const int pl = pg - c_off[lv];
  const int Wl = c_W[lv];
  const int g = c0 >> 3;
  const float* st = &stats[(((size_t)br*NLEV + lv)*32 + g)*2];
  const float cnt = 8.f * (float)c_HW[lv];
  const float mean = st[0] / cnt;
  const float var  = st[1] / cnt - mean*mean;
  const float rstd = rsqrtf(var + 1e-5f);
  const float* Y  = br ? Yb : Yc;
  const float* gw = br ? gwb : gwc;
  const float* gb = br ? gbb : gbc;
  u16* X = br ? Xb : Xc;
  const float* y = &Y[(size_t)pg*CCH + c0];
  const int h = pl / Wl, wi = pl - h*Wl;
  const size_t pidx = (size_t)(c_poff[lv] + (h+1)*(Wl+2) + (wi+1));
  union { u16 u[8]; uint4 v; } pk;
  #pragma unroll
  for (int i = 0; i < 8; i++) {
    const float v = (y[i] - mean)*rstd*gw[c0+i] + gb[c0+i];
    pk.u[i] = f2bf(fmaxf(v, 0.f));
  }
  *(uint4*)&X[(size_t)(c0 >> 6)*PLS + pidx*64 + (c0 & 63)] = pk.v;
}

// fp32 NCHW feats -> bf16 planar padded
__global__ __launch_bounds__(256) void feat2bf(
    const float* __restrict__ p3, const float* __restrict__ p4,
    const float* __restrict__ p5, const float* __restrict__ p6,
    const float* __restrict__ p7, u16* __restrict__ X)
{
  const int t = blockIdx.x * 256 + threadIdx.x;
  if (t >= P_TOT * 32) return;
  const int pg = t >> 5, c0 = (t & 31) << 3;
  int lv = 0;
  #pragma unroll
  for (int i = 1; i < NLEV; i++) if (pg >= c_off[i]) lv = i;
  const int pl = pg - c_off[lv];
  const float* src = lv==0 ? p3 : lv==1 ? p4 : lv==2 ? p5 : lv==3 ? p6 : p7;
  const int HW = c_HW[lv], Wl = c_W[lv];
  const int h = pl / Wl, wi = pl - h*Wl;
  const size_t pidx = (size_t)(c_poff[lv] + (h+1)*(Wl+2) + (wi+1));
  union { u16 u[8]; uint4 v; } pk;
  #pragma unroll
  for (int i = 0; i < 8; i++)
    pk.u[i] = f2bf(src[(size_t)(c0+i)*HW + pl]);
  *(uint4*)&X[(size_t)(c0 >> 6)*PLS + pidx*64 + (c0 & 63)] = pk.v;
}

// tower weights [l][co][ci][9] fp32 -> A-register packed bf16 layout:
// d = l*589824 + s*16384 + (co>>5)*2048 + (kl>>5)*1024 + ((co>>4)&1)*512
//     + ((kl>>3)&3)*128 + (co&15)*8 + (kl&7);  k = tap*256+ci, s=k>>6, kl=k&63.
__global__ __launch_bounds__(256) void wconv(
    const float* __restrict__ cw, const float* __restrict__ bw,
    u16* __restrict__ Wc, u16* __restrict__ Wb)
{
  const size_t N = (size_t)4*256*KTOT;
  const size_t t = (size_t)blockIdx.x * 256 + threadIdx.x;
  if (t >= 2*N) return;
  const float* src = (t < N) ? cw : bw;
  u16* dst = (t < N) ? Wc : Wb;
  const size_t i = (t < N) ? t : t - N;
  const size_t lc = i / KTOT;
  const int kk = (int)(i - lc*KTOT);
  const int l = (int)(lc >> 8), co = (int)(lc & 255);
  const int tap = kk >> 8, ci = kk & 255;
  const int s = kk >> 6, kl = kk & 63;
  const size_t d = (size_t)l*589824 + (size_t)s*16384 +
      (size_t)((co >> 5)*2048 + (kl >> 5)*1024 + ((co >> 4) & 1)*512 +
               ((kl >> 3) & 3)*128 + (co & 15)*8 + (kl & 7));
  dst[d] = f2bf(src[(lc*256 + ci)*9 + tap]);
}

// head weights -> A-register packed (cls: 80 rows; box: 4 pred + 1 iou),
// 128 co rows, per-stage size 8192 u16.
__global__ __launch_bounds__(256) void hconv(
    const float* __restrict__ sw, const float* __restrict__ pw,
    const float* __restrict__ iw, u16* __restrict__ Whc, u16* __restrict__ Whb)
{
  const int N = 128 * KTOT;
  const int t = blockIdx.x * 256 + threadIdx.x;
  if (t >= 2*N) return;
  const int i = (t < N) ? t : t - N;
  const int co = i / KTOT, kk = i - co*KTOT;
  const int tap = kk >> 8, ci = kk & 255;
  const int s = kk >> 6, kl = kk & 63;
  const size_t d = (size_t)s*8192 +
      (size_t)((co >> 5)*2048 + (kl >> 5)*1024 + ((co >> 4) & 1)*512 +
               ((kl >> 3) & 3)*128 + (co & 15)*8 + (kl & 7));
  float v = 0.f;
  if (t < N) {
    if (co < 80) v = sw[(co*256 + ci)*9 + tap];
    Whc[d] = f2bf(v);
  } else {
    if (co < 4)       v = pw[(co*256 + ci)*9 + tap];
    else if (co == 4) v = iw[ci*9 + tap];
    Whb[d] = f2bf(v);
  }
}

extern "C" void kernel_launch(void* const* d_in, const int* in_sizes, int n_in,
                              void* d_out, int out_size, void* d_ws, size_t ws_size,
                              hipStream_t stream)
{
  const float* p3      = (const float*)d_in[0];
  const float* p4      = (const float*)d_in[1];
  const float* p5      = (const float*)d_in[2];
  const float* p6      = (const float*)d_in[3];
  const float* p7      = (const float*)d_in[4];
  const float* cls_w   = (const float*)d_in[5];
  const float* cls_b   = (const float*)d_in[6];
  const float* cls_gw  = (const float*)d_in[7];
  const float* cls_gb  = (const float*)d_in[8];
  const float* box_w   = (const float*)d_in[9];
  const float* box_b   = (const float*)d_in[10];
  const float* box_gw  = (const float*)d_in[11];
  const float* box_gb  = (const float*)d_in[12];
  const float* score_w = (const float*)d_in[13];
  const float* score_b = (const float*)d_in[14];
  const float* pred_w  = (const float*)d_in[15];
  const float* pred_b  = (const float*)d_in[16];
  const float* iou_w   = (const float*)d_in[17];
  const float* iou_b   = (const float*)d_in[18];
  const float* scales  = (const float*)d_in[19];
  float* out = (float*)d_out;

  char* w = (char*)d_ws;
  size_t o = 0;
  auto alloc = [&](size_t b) { void* p = w + o; o += (b + 255) & ~(size_t)255; return p; };
  // X buffers + stats first: zeroed by ONE memset (all 256B multiples)
  u16*   XF = (u16*)alloc((size_t)PP_TOT*CCH*2);   // planar [4][PP_TOT][64]
  u16*   XC = (u16*)alloc((size_t)PP_TOT*CCH*2);
  u16*   XB = (u16*)alloc((size_t)PP_TOT*CCH*2);
  float* ST = (float*)alloc((size_t)4*2*NLEV*32*2*4);   // [layer][br][lv][32][2]
  u16*  WRC = (u16*)alloc((size_t)4*256*KTOT*2);
  u16*  WRB = (u16*)alloc((size_t)4*256*KTOT*2);
  u16*  WHC = (u16*)alloc((size_t)128*KTOT*2);
  u16*  WHB = (u16*)alloc((size_t)128*KTOT*2);
  float* YC = (float*)alloc((size_t)P_TOT*CCH*4);
  float* YB = (float*)alloc((size_t)P_TOT*CCH*4);

  // zero padded activation borders + all layers' GN stats in one shot
  hipMemsetAsync(XF, 0, (size_t)3*PP_TOT*CCH*2 + (size_t)4*2*NLEV*32*2*4, stream);

  wconv<<<dim3((unsigned)(((size_t)2*4*256*KTOT + 255)/256)), 256, 0, stream>>>(cls_w, box_w, WRC, WRB);
  hconv<<<dim3((2*128*KTOT + 255)/256), 256, 0, stream>>>(score_w, pred_w, iou_w, WHC, WHB);
  feat2bf<<<dim3((P_TOT*32 + 255)/256), 256, 0, stream>>>(p3, p4, p5, p6, p7, XF);

  const u16* xci = XF; const u16* xbi = XF;
  for (int l = 0; l < 4; l++) {
    float* STl = ST + (size_t)l*2*NLEV*32*2;
    gemm_conv<0><<<dim3(1184), 64, 0, stream>>>(
        xci, xbi, WRC + (size_t)l*589824, WRB + (size_t)l*589824,
        cls_b + l*256, box_b + l*256, YC, YB, STl,
        nullptr, nullptr, nullptr, nullptr);
    gn_relu<<<dim3((2*P_TOT*32 + 255)/256), 256, 0, stream>>>(
        YC, YB, STl, cls_gw + l*256, cls_gb + l*256, box_gw + l*256, box_gb + l*256,
        XC, XB);
    xci = XC; xbi = XB;
  }
  gemm_conv<1><<<dim3(296), 64, 0, stream>>>(
      xci, xbi, WHC, WHB, score_b, nullptr, nullptr, nullptr, nullptr,
      pred_b, iou_b, scales, out);
}

// Round 8
// 470.691 us; speedup vs baseline: 1.0284x; 1.0284x over previous
//
#include <hip/hip_runtime.h>

typedef unsigned short u16;
typedef __attribute__((ext_vector_type(8))) short bf16x8;   // 8 x bf16 (4 VGPRs)
typedef __attribute__((ext_vector_type(4))) float f32x4;

#define NLEV 5
#define CCH 256
#define KTOT 2304            // 9 taps * 256 ci
#define P_TOT 8525           // sum HW
#define PP_TOT 9165          // sum (H+2)*(W+2)
#define PLS (PP_TOT*64)      // activation plane stride (u16), 4 planes of 64 ci

__constant__ int   c_HW[NLEV]     = {6400, 1600, 400, 100, 25};
__constant__ int   c_W[NLEV]      = {80, 40, 20, 10, 5};    // H == W (square)
__constant__ int   c_off[NLEV]    = {0, 6400, 8000, 8400, 8500};
__constant__ int   c_poff[NLEV]   = {0, 6724, 8488, 8972, 9116};
__constant__ int   c_tls[NLEV+1]  = {0, 50, 65, 71, 73, 74};  // 16x8 tile starts
__constant__ int   c_ntx[NLEV]    = {5, 3, 2, 1, 1};          // tiles across
__constant__ float c_stridef[NLEV]= {8.f, 16.f, 32.f, 64.f, 128.f};

__device__ __forceinline__ u16 f2bf(float f){
  union { float f; unsigned u; } v; v.f = f;
  unsigned r = v.u + 0x7fffu + ((v.u >> 16) & 1u);   // RNE
  return (u16)(r >> 16);
}

// ---------------------------------------------------------------------------
// R8: R7's decoupled 1-wave streams with the two measured defects fixed.
// R7 counters: FETCH_SIZE 36MB/dispatch ~ 8x the X buffer (bid=j*74+p put
// the 8 g2-waves reading the SAME B pixels on 8 different XCDs -> every X
// line filled into 8 L2s; weights spread across all XCDs, >4MB/XCD ->
// thrash, A/B at L3 latency) and VGPR_Count 112 < the 192 needed for the
// dual register sets (compiler sank the prefetch loads next to their uses,
// serializing load->wait->compute per stage).
// Fix 1 (XCD grouping by ptile): with round-robin wg->XCD (xcd = bid%8),
// remap so ALL 16 (br,g2) blocks of one ptile share bid%8:
//   bid = low + 8*(j + NJ*phi), ptile = low + 8*phi  (guard ptile>=74)
// Per-XCD L2 working set = weights 2.36MB + ~9 ptiles' halo slices ~1.7MB
// ~ 4MB = resident; X lines filled once, not 8x. Bijective on real work.
// Fix 2 (pipeline pin): ld(k+1); sched_barrier(0); cmp(k) - loads cannot
// sink past the MFMA cluster, forcing the dual-set depth-1 pipeline; the
// compiler's auto-waitcnt then waits only on stage k's loads while k+1's
// 16 are in flight.
// Everything else = R7: zero LDS, zero barriers; A and B global->register;
// 24 half-titer stages (u=k>>1: cc=u/3, dw=u%3, s=k&1); B rows 0..9 cover
// the 3 dh taps; GN stats wave-reduced then atomicAdd to global. MFMA
// order bit-identical -> absmax must stay exactly 0.625.
// MODE 0: towers, grid 1280 (=8*16*10), NJ=16: j = br*8+g2.
// MODE 1: heads,  grid 320  (=8*4*10),  NJ=4:  j<3 -> br0 g2=j (m<80);
//         j==3 -> br1 g2=0 (pred m<4 + iou m==4).
// ---------------------------------------------------------------------------
template<int MODE>
__global__ __launch_bounds__(64)
__attribute__((amdgpu_waves_per_eu(2, 2)))
void gemm_conv(
    const u16* __restrict__ Xc, const u16* __restrict__ Xb,
    const u16* __restrict__ Wc, const u16* __restrict__ Wb,
    const float* __restrict__ bc, const float* __restrict__ bb,
    float* __restrict__ Yc, float* __restrict__ Yb,
    float* __restrict__ stats,
    const float* __restrict__ predb, const float* __restrict__ ioub,
    const float* __restrict__ scales, float* __restrict__ out)
{
  const int bid = blockIdx.x;
  const int low = bid & 7;
  const int r   = bid >> 3;
  const int j   = (MODE == 0) ? (r & 15) : (r & 3);
  const int phi = (MODE == 0) ? (r >> 4) : (r >> 2);
  const int ptile = low + 8*phi;
  if (ptile >= 74) return;                     // pad blocks (no LDS/barrier)
  const int g2 = (MODE == 0) ? (j & 7) : (j < 3 ? j : 0);
  const int br = (MODE == 0) ? (j >> 3) : (j == 3 ? 1 : 0);

  int lv = 0;
  #pragma unroll
  for (int i = 1; i < NLEV; i++) if (ptile >= c_tls[i]) lv = i;
  const int tidx = ptile - c_tls[lv];
  const int ntx = c_ntx[lv];
  const int ty0 = (tidx / ntx) * 8, tx0 = (tidx - (tidx / ntx) * ntx) * 16;
  const int W = c_W[lv], wrow2 = W + 2;

  const int ln = threadIdx.x & 63;
  const int quad = ln >> 4, l15 = ln & 15;

  const u16* __restrict__ X  = br ? Xb : Xc;   // planar activations
  const u16* __restrict__ WA = br ? Wb : Wc;   // packed weights

  const int SZ = (MODE == 0) ? 16384 : 8192;   // per-stage A u16s
  const u16* aln = WA + (size_t)(g2*2048 + ln*8);
  // per-lane B base: pixel (ty0, tx0+l15) of padded plane, ci-group quad
  const u16* xb0 = X + (size_t)(c_poff[lv] + ty0*wrow2 + tx0 + l15) * 64
                     + quad*8;
  const int brow = wrow2 * 64;                 // B row stride (u16)

  f32x4 acc[2][8];
  #pragma unroll
  for (int i = 0; i < 2; i++)
    #pragma unroll
    for (int jj = 0; jj < 8; jj++) acc[i][jj] = (f32x4){0.f, 0.f, 0.f, 0.f};

  // pipeline register sets (static indexing only)
  bf16x8 aA[6], bA[10], aB[6], bB[10];

  auto ldStage = [&](int k, bf16x8 (&a)[6], bf16x8 (&b)[10]) {
    const int u = k >> 1, s = k & 1;
    const int cc = u / 3, dw = u - cc*3;
    #pragma unroll
    for (int dh = 0; dh < 3; dh++)
      #pragma unroll
      for (int mt = 0; mt < 2; mt++)
        a[dh*2 + mt] = *(const bf16x8*)
            (aln + (size_t)((dh*3 + dw)*4 + cc) * SZ + (s*2 + mt)*512);
    const u16* bp = xb0 + (size_t)cc * PLS + (size_t)dw * 64 + s*32;
    #pragma unroll
    for (int n2 = 0; n2 < 10; n2++)
      b[n2] = *(const bf16x8*)(bp + (size_t)n2 * brow);
  };
  auto cmpStage = [&](bf16x8 (&a)[6], bf16x8 (&b)[10]) {
    #pragma unroll
    for (int dh = 0; dh < 3; dh++)
      #pragma unroll
      for (int mt = 0; mt < 2; mt++)
        #pragma unroll
        for (int nt = 0; nt < 8; nt++)
          acc[mt][nt] = __builtin_amdgcn_mfma_f32_16x16x32_bf16(
              a[dh*2 + mt], b[nt + dh], acc[mt][nt], 0, 0, 0);
  };

  // ---- K-loop: 24 stages, depth-1 register pipeline, issue-order pinned ----
  ldStage(0, aA, bA);
  #pragma unroll 1
  for (int k = 0; k < 24; k += 2) {
    if (k + 1 < 24) ldStage(k + 1, aB, bB);
    __builtin_amdgcn_sched_barrier(0);         // loads stay ABOVE cmp(k)
    cmpStage(aA, bA);
    if (k + 2 < 24) ldStage(k + 2, aA, bA);
    __builtin_amdgcn_sched_barrier(0);
    cmpStage(aB, bB);
  }

  const int gx = tx0 + l15;
  if (MODE == 0) {
    const float* __restrict__ bias = br ? bb : bc;
    float* __restrict__ Y = br ? Yb : Yc;
    #pragma unroll
    for (int mt = 0; mt < 2; mt++) {
      const int mrow = g2*32 + mt*16 + quad*4;          // 0..255 global co
      const f32x4 bv = *(const f32x4*)&bias[mrow];
      float s = 0.f, sq = 0.f;
      #pragma unroll
      for (int nt = 0; nt < 8; nt++) {
        const int gy = ty0 + nt;
        f32x4 v = acc[mt][nt] + bv;
        if (gy < W && gx < W) {
          const size_t n = (size_t)(c_off[lv] + gy*W + gx);
          *(f32x4*)&Y[n*CCH + mrow] = v;
          #pragma unroll
          for (int r2 = 0; r2 < 4; r2++) { s += v[r2]; sq += v[r2]*v[r2]; }
        }
      }
      #pragma unroll
      for (int o = 1; o < 16; o <<= 1) { s += __shfl_xor(s, o); sq += __shfl_xor(sq, o); }
      if (l15 == 0) {
        const int G = g2*4 + mt*2 + (quad >> 1);        // global 8-ch group
        atomicAdd(&stats[((br*NLEV + lv)*32 + G)*2 + 0], s);
        atomicAdd(&stats[((br*NLEV + lv)*32 + G)*2 + 1], sq);
      }
    }
  } else {
    const float scl = scales[lv];
    const float stf = c_stridef[lv];
    #pragma unroll
    for (int mt = 0; mt < 2; mt++) {
      const int mr0 = g2*32 + mt*16 + quad*4;
      if (mr0 >= 85) continue;
      #pragma unroll
      for (int nt = 0; nt < 8; nt++) {
        const int gy = ty0 + nt;
        if (gy >= W || gx >= W) continue;
        const size_t n = (size_t)(c_off[lv] + gy*W + gx);
        const f32x4 v = acc[mt][nt];
        #pragma unroll
        for (int r2 = 0; r2 < 4; r2++) {
          const int m = mr0 + r2;
          if (br == 0) {
            if (m < 80) out[n*85 + m] = v[r2] + bc[m];         // logits
          } else {
            if (m < 4) {
              const float t = (v[r2] + predb[m]) * scl;        // Scale module
              out[n*85 + 80 + m] = fmaxf(t, 0.f) * stf;        // relu * stride
            } else if (m == 4) {
              out[n*85 + 84] = v[r2] + ioub[0];                // iou
            }
          }
        }
      }
    }
  }
}

// GN finalize + affine + ReLU + bf16 cast into PLANAR padded layout.
// Y already includes conv bias.
__global__ __launch_bounds__(256) void gn_relu(
    const float* __restrict__ Yc, const float* __restrict__ Yb,
    const float* __restrict__ stats,
    const float* __restrict__ gwc, const float* __restrict__ gbc,
    const float* __restrict__ gwb, const float* __restrict__ gbb,
    u16* __restrict__ Xc, u16* __restrict__ Xb)
{
  const int t = blockIdx.x * 256 + threadIdx.x;
  if (t >= 2 * P_TOT * 32) return;
  const int br = t / (P_TOT * 32);
  const int r  = t - br * (P_TOT * 32);
  const int pg = r >> 5;
  const int c0 = (r & 31) << 3;
  int lv = 0;
  #pragma unroll
  for (int i = 1; i < NLEV; i++) if (pg >= c_off[i]) lv = i;
  const int pl = pg - c_off[lv];
  const int Wl = c_W[lv];
  const int g = c0 >> 3;
  const float* st = &stats[(((size_t)br*NLEV + lv)*32 + g)*2];
  const float cnt = 8.f * (float)c_HW[lv];
  const float mean = st[0] / cnt;
  const float var  = st[1] / cnt - mean*mean;
  const float rstd = rsqrtf(var + 1e-5f);
  const float* Y  = br ? Yb : Yc;
  const float* gw = br ? gwb : gwc;
  const float* gb = br ? gbb : gbc;
  u16* X = br ? Xb : Xc;
  const float* y = &Y[(size_t)pg*CCH + c0];
  const int h = pl / Wl, wi = pl - h*Wl;
  const size_t pidx = (size_t)(c_poff[lv] + (h+1)*(Wl+2) + (wi+1));
  union { u16 u[8]; uint4 v; } pk;
  #pragma unroll
  for (int i = 0; i < 8; i++) {
    const float v = (y[i] - mean)*rstd*gw[c0+i] + gb[c0+i];
    pk.u[i] = f2bf(fmaxf(v, 0.f));
  }
  *(uint4*)&X[(size_t)(c0 >> 6)*PLS + pidx*64 + (c0 & 63)] = pk.v;
}

// fp32 NCHW feats -> bf16 planar padded
__global__ __launch_bounds__(256) void feat2bf(
    const float* __restrict__ p3, const float* __restrict__ p4,
    const float* __restrict__ p5, const float* __restrict__ p6,
    const float* __restrict__ p7, u16* __restrict__ X)
{
  const int t = blockIdx.x * 256 + threadIdx.x;
  if (t >= P_TOT * 32) return;
  const int pg = t >> 5, c0 = (t & 31) << 3;
  int lv = 0;
  #pragma unroll
  for (int i = 1; i < NLEV; i++) if (pg >= c_off[i]) lv = i;
  const int pl = pg - c_off[lv];
  const float* src = lv==0 ? p3 : lv==1 ? p4 : lv==2 ? p5 : lv==3 ? p6 : p7;
  const int HW = c_HW[lv], Wl = c_W[lv];
  const int h = pl / Wl, wi = pl - h*Wl;
  const size_t pidx = (size_t)(c_poff[lv] + (h+1)*(Wl+2) + (wi+1));
  union { u16 u[8]; uint4 v; } pk;
  #pragma unroll
  for (int i = 0; i < 8; i++)
    pk.u[i] = f2bf(src[(size_t)(c0+i)*HW + pl]);
  *(uint4*)&X[(size_t)(c0 >> 6)*PLS + pidx*64 + (c0 & 63)] = pk.v;
}

// tower weights [l][co][ci][9] fp32 -> A-register packed bf16 layout:
// d = l*589824 + s*16384 + (co>>5)*2048 + (kl>>5)*1024 + ((co>>4)&1)*512
//     + ((kl>>3)&3)*128 + (co&15)*8 + (kl&7);  k = tap*256+ci, s=k>>6, kl=k&63.
__global__ __launch_bounds__(256) void wconv(
    const float* __restrict__ cw, const float* __restrict__ bw,
    u16* __restrict__ Wc, u16* __restrict__ Wb)
{
  const size_t N = (size_t)4*256*KTOT;
  const size_t t = (size_t)blockIdx.x * 256 + threadIdx.x;
  if (t >= 2*N) return;
  const float* src = (t < N) ? cw : bw;
  u16* dst = (t < N) ? Wc : Wb;
  const size_t i = (t < N) ? t : t - N;
  const size_t lc = i / KTOT;
  const int kk = (int)(i - lc*KTOT);
  const int l = (int)(lc >> 8), co = (int)(lc & 255);
  const int tap = kk >> 8, ci = kk & 255;
  const int s = kk >> 6, kl = kk & 63;
  const size_t d = (size_t)l*589824 + (size_t)s*16384 +
      (size_t)((co >> 5)*2048 + (kl >> 5)*1024 + ((co >> 4) & 1)*512 +
               ((kl >> 3) & 3)*128 + (co & 15)*8 + (kl & 7));
  dst[d] = f2bf(src[(lc*256 + ci)*9 + tap]);
}

// head weights -> A-register packed (cls: 80 rows; box: 4 pred + 1 iou),
// 128 co rows, per-stage size 8192 u16.
__global__ __launch_bounds__(256) void hconv(
    const float* __restrict__ sw, const float* __restrict__ pw,
    const float* __restrict__ iw, u16* __restrict__ Whc, u16* __restrict__ Whb)
{
  const int N = 128 * KTOT;
  const int t = blockIdx.x * 256 + threadIdx.x;
  if (t >= 2*N) return;
  const int i = (t < N) ? t : t - N;
  const int co = i / KTOT, kk = i - co*KTOT;
  const int tap = kk >> 8, ci = kk & 255;
  const int s = kk >> 6, kl = kk & 63;
  const size_t d = (size_t)s*8192 +
      (size_t)((co >> 5)*2048 + (kl >> 5)*1024 + ((co >> 4) & 1)*512 +
               ((kl >> 3) & 3)*128 + (co & 15)*8 + (kl & 7));
  float v = 0.f;
  if (t < N) {
    if (co < 80) v = sw[(co*256 + ci)*9 + tap];
    Whc[d] = f2bf(v);
  } else {
    if (co < 4)       v = pw[(co*256 + ci)*9 + tap];
    else if (co == 4) v = iw[ci*9 + tap];
    Whb[d] = f2bf(v);
  }
}

extern "C" void kernel_launch(void* const* d_in, const int* in_sizes, int n_in,
                              void* d_out, int out_size, void* d_ws, size_t ws_size,
                              hipStream_t stream)
{
  const float* p3      = (const float*)d_in[0];
  const float* p4      = (const float*)d_in[1];
  const float* p5      = (const float*)d_in[2];
  const float* p6      = (const float*)d_in[3];
  const float* p7      = (const float*)d_in[4];
  const float* cls_w   = (const float*)d_in[5];
  const float* cls_b   = (const float*)d_in[6];
  const float* cls_gw  = (const float*)d_in[7];
  const float* cls_gb  = (const float*)d_in[8];
  const float* box_w   = (const float*)d_in[9];
  const float* box_b   = (const float*)d_in[10];
  const float* box_gw  = (const float*)d_in[11];
  const float* box_gb  = (const float*)d_in[12];
  const float* score_w = (const float*)d_in[13];
  const float* score_b = (const float*)d_in[14];
  const float* pred_w  = (const float*)d_in[15];
  const float* pred_b  = (const float*)d_in[16];
  const float* iou_w   = (const float*)d_in[17];
  const float* iou_b   = (const float*)d_in[18];
  const float* scales  = (const float*)d_in[19];
  float* out = (float*)d_out;

  char* w = (char*)d_ws;
  size_t o = 0;
  auto alloc = [&](size_t b) { void* p = w + o; o += (b + 255) & ~(size_t)255; return p; };
  // X buffers + stats first: zeroed by ONE memset (all 256B multiples)
  u16*   XF = (u16*)alloc((size_t)PP_TOT*CCH*2);   // planar [4][PP_TOT][64]
  u16*   XC = (u16*)alloc((size_t)PP_TOT*CCH*2);
  u16*   XB = (u16*)alloc((size_t)PP_TOT*CCH*2);
  float* ST = (float*)alloc((size_t)4*2*NLEV*32*2*4);   // [layer][br][lv][32][2]
  u16*  WRC = (u16*)alloc((size_t)4*256*KTOT*2);
  u16*  WRB = (u16*)alloc((size_t)4*256*KTOT*2);
  u16*  WHC = (u16*)alloc((size_t)128*KTOT*2);
  u16*  WHB = (u16*)alloc((size_t)128*KTOT*2);
  float* YC = (float*)alloc((size_t)P_TOT*CCH*4);
  float* YB = (float*)alloc((size_t)P_TOT*CCH*4);

  // zero padded activation borders + all layers' GN stats in one shot
  hipMemsetAsync(XF, 0, (size_t)3*PP_TOT*CCH*2 + (size_t)4*2*NLEV*32*2*4, stream);

  wconv<<<dim3((unsigned)(((size_t)2*4*256*KTOT + 255)/256)), 256, 0, stream>>>(cls_w, box_w, WRC, WRB);
  hconv<<<dim3((2*128*KTOT + 255)/256), 256, 0, stream>>>(score_w, pred_w, iou_w, WHC, WHB);
  feat2bf<<<dim3((P_TOT*32 + 255)/256), 256, 0, stream>>>(p3, p4, p5, p6, p7, XF);

  const u16* xci = XF; const u16* xbi = XF;
  for (int l = 0; l < 4; l++) {
    float* STl = ST + (size_t)l*2*NLEV*32*2;
    gemm_conv<0><<<dim3(1280), 64, 0, stream>>>(
        xci, xbi, WRC + (size_t)l*589824, WRB + (size_t)l*589824,
        cls_b + l*256, box_b + l*256, YC, YB, STl,
        nullptr, nullptr, nullptr, nullptr);
    gn_relu<<<dim3((2*P_TOT*32 + 255)/256), 256, 0, stream>>>(
        YC, YB, STl, cls_gw + l*256, cls_gb + l*256, box_gw + l*256, box_gb + l*256,
        XC, XB);
    xci = XC; xbi = XB;
  }
  gemm_conv<1><<<dim3(320), 64, 0, stream>>>(
      xci, xbi, WHC, WHB, score_b, nullptr, nullptr, nullptr, nullptr,
      pred_b, iou_b, scales, out);
}

// Round 9
// 422.848 us; speedup vs baseline: 1.1448x; 1.1131x over previous
//
#include <hip/hip_runtime.h>

typedef unsigned short u16;
typedef __attribute__((ext_vector_type(8))) short bf16x8;   // 8 x bf16 (4 VGPRs)
typedef __attribute__((ext_vector_type(4))) float f32x4;

#define NLEV 5
#define CCH 256
#define KTOT 2304            // 9 taps * 256 ci
#define P_TOT 8525           // sum HW
#define PP_TOT 9165          // sum (H+2)*(W+2)
#define PLS (PP_TOT*64)      // activation plane stride (u16), 4 planes of 64 ci
#define HSTR 11776           // halo LDS plane (u16) = 23 slabs * 512 (23552 B)

__constant__ int   c_HW[NLEV]     = {6400, 1600, 400, 100, 25};
__constant__ int   c_W[NLEV]      = {80, 40, 20, 10, 5};    // H == W (square)
__constant__ int   c_off[NLEV]    = {0, 6400, 8000, 8400, 8500};
__constant__ int   c_poff[NLEV]   = {0, 6724, 8488, 8972, 9116};
__constant__ int   c_tls[NLEV+1]  = {0, 50, 65, 71, 73, 74};  // 16x8 tile starts
__constant__ int   c_ntx[NLEV]    = {5, 3, 2, 1, 1};          // tiles across
__constant__ float c_stridef[NLEV]= {8.f, 16.f, 32.f, 64.f, 128.f};

__device__ __forceinline__ u16 f2bf(float f){
  union { float f; unsigned u; } v; v.f = f;
  unsigned r = v.u + 0x7fffu + ((v.u >> 16) & 1u);   // RNE
  return (u16)(r >> 16);
}

// async global->LDS: 64 lanes x 16B; HW writes lane i to ldsbase + i*16.
__device__ __forceinline__ void g2l16(const u16* g, u16* l, int lane){
#if defined(__has_builtin)
#if __has_builtin(__builtin_amdgcn_global_load_lds)
  __builtin_amdgcn_global_load_lds(
      (const __attribute__((address_space(1))) unsigned int*)g,
      (__attribute__((address_space(3))) unsigned int*)l, 16, 0, 0);
  return;
#endif
#endif
  *(uint4*)(l + lane*8) = *(const uint4*)g;  // fallback: sync copy
}

// s_waitcnt imm (gfx9: vm[3:0] bits3:0, vm[5:4] bits15:14, exp[6:4], lgkm[11:8])
#define WAIT_VM0   0x0F70   // vmcnt(0)

// ---------------------------------------------------------------------------
// R9: MORE WAVES, LESS LDS. Diagnosis across R2-R8: towers had only 1184
// waves for 1024 SIMDs (~1.1 waves/SIMD of AVAILABLE work) - every exposed
// latency (ds_read ~120cy, staging, barriers) sat on the critical path
// because no second wave existed to fill it; that is why six structurally
// different fixes were all flat at ~330. (R7/R8's no-LDS arc additionally
// amplified B cache traffic 8x -> worse.) This version doubles TLP:
//  - each 32-co wave splits into TWO 16-co waves (2368 waves, 2.3/SIMD);
//    acc 64->32 VGPR, A-dbuf 96->48: ~160 total, __launch_bounds__(256,3)
//    -> 12 waves/CU (3/SIMD) co-resident across 3 blocks/CU
//  - halo plane SINGLE-buffered (23.5 KB, was 47): staged at each cc
//    boundary behind a 2-barrier dance; the exposed staging latency is
//    covered by the other co-resident blocks (the new TLP).
// Per-wave K-loop (order preserved from R4): 12 titers u=(cc,dw); B rows
// 0..9 ds_read once per sub, reused across the 3 dh taps; A frags double-
// buffered global->reg (afA/afB, static indices). Per-acc MFMA sequence
// (values + order over cc,dw,sub,dh) is bit-identical to R2-R6; only the
// wave->co mapping changed -> absmax must stay exactly 0.625.
// cc boundary (u=3,6,9): sched_barrier; s_barrier (plane cc-1 consumed);
// stageH(cc); vmcnt(0) (my 6 slabs landed; in-flight A also drains, it was
// issued a titer ago); s_barrier (all waves' slabs landed).
// MODE 0: towers, grid (74,4,2) x 256thr: wave wv covers co mtile*64+wv*16.
// MODE 1: heads,  grid (74,3,1): y<2 -> br0 mtile=y (m<80 guard);
//         y==2 -> br1 mtile 0 (pred m<4 + iou m==4).
// GN stats: 16-lane shfl reduce, then atomicAdd straight to global stats.
// ---------------------------------------------------------------------------
template<int MODE>
__global__ __launch_bounds__(256, 3) void gemm_conv(
    const u16* __restrict__ Xc, const u16* __restrict__ Xb,
    const u16* __restrict__ Wc, const u16* __restrict__ Wb,
    const float* __restrict__ bc, const float* __restrict__ bb,
    float* __restrict__ Yc, float* __restrict__ Yb,
    float* __restrict__ stats,
    const float* __restrict__ predb, const float* __restrict__ ioub,
    const float* __restrict__ scales, float* __restrict__ out)
{
  __shared__ u16 hB[HSTR];          // 23552 B: SINGLE halo plane

  const int ptile = blockIdx.x;
  const int job   = (MODE == 0) ? 0 : blockIdx.y;
  const int mtile = (MODE == 0) ? blockIdx.y : (job == 1 ? 1 : 0);
  const int br    = (MODE == 0) ? blockIdx.z : (job == 2 ? 1 : 0);
  int lv = 0;
  #pragma unroll
  for (int i = 1; i < NLEV; i++) if (ptile >= c_tls[i]) lv = i;
  const int tidx = ptile - c_tls[lv];
  const int ntx = c_ntx[lv];
  const int ty0 = (tidx / ntx) * 8, tx0 = (tidx - (tidx / ntx) * ntx) * 16;
  const int W = c_W[lv], wrow2 = W + 2;

  const int tid = threadIdx.x, wv = tid >> 6, ln = tid & 63;
  const int quad = ln >> 4, l15 = ln & 15;
  const int mtSel = wv & 1;                    // which 16-co half of g2
  const int g2 = mtile*2 + (wv >> 1);          // 32-co group index

  const u16* __restrict__ X  = br ? Xb : Xc;   // planar activations
  const u16* __restrict__ WA = br ? Wb : Wc;   // packed weights

  const int SZ = (MODE == 0) ? 16384 : 8192;   // per-stage A u16s
  const u16* aln = WA + (size_t)(g2*2048 + ln*8);

  // Halo staging: slab j = wv+4i (i<6), j>22 -> idempotent dup (6 loads/wave)
  auto stageH = [&](int plane) {
    const size_t cof = (size_t)plane * PLS;
    #pragma unroll
    for (int i = 0; i < 6; i++) {
      int jj = wv + 4*i;
      if (jj > 22) jj -= 4;                    // wv3,i=5 -> slab 19 (dup)
      const int item = jj*64 + ln;
      int hp = item >> 3; if (hp >= 180) hp -= 180;
      const int g = item & 7;
      const int hy = hp / 18, hx = hp - hy*18;
      const int prow = c_poff[lv] + (ty0 + hy)*wrow2 + tx0 + hx;
      g2l16(X + (size_t)prow*64 + ((g ^ (hp & 7)) << 3) + cof,
            hB + jj*512, ln);
    }
  };

  f32x4 acc[8];
  #pragma unroll
  for (int jj = 0; jj < 8; jj++) acc[jj] = (f32x4){0.f, 0.f, 0.f, 0.f};

  // A fragment DOUBLE BUFFER: [dh][sub] x2 = 48 VGPR, static indexing only.
  bf16x8 afA[3][2], afB[3][2];
  auto loadA = [&](int cc_, int dw_, bf16x8 (&af)[3][2]) {
    #pragma unroll
    for (int dh = 0; dh < 3; dh++) {
      const u16* p = aln + (size_t)((dh*3 + dw_)*4 + cc_) * SZ;
      #pragma unroll
      for (int sub = 0; sub < 2; sub++)
        af[dh][sub] = *(const bf16x8*)(p + (sub*2 + mtSel)*512);
    }
  };

  // ---- prologue: halo plane 0 + A(0); one barrier ----
  stageH(0);
  loadA(0, 0, afA);
  __builtin_amdgcn_s_waitcnt(WAIT_VM0);
  __syncthreads();                             // plane 0 + regs valid

  // ---- K-loop: 12 titers u = cc*3 + dw, unrolled by 2 for the A dbuf ----
  int cc = 0, dw = 0;
  auto body = [&](int u, bf16x8 (&cur)[3][2], bf16x8 (&nxt)[3][2]) {
    if (dw == 0 && cc > 0) {                   // u = 3,6,9: restage plane
      __builtin_amdgcn_sched_barrier(0);
      __builtin_amdgcn_s_barrier();            // plane cc-1 fully consumed
      __builtin_amdgcn_sched_barrier(0);
      stageH(cc);
      __builtin_amdgcn_s_waitcnt(WAIT_VM0);    // my slabs landed (A too)
      __builtin_amdgcn_sched_barrier(0);
      __builtin_amdgcn_s_barrier();            // everyone's slabs landed
      __builtin_amdgcn_sched_barrier(0);
    }
    {                                          // prefetch A(u+1) -> nxt
      int dwn = dw + 1, ccn = cc;
      if (dwn == 3) { dwn = 0; ccn++; }
      if (u < 11) loadA(ccn, dwn, nxt);
    }
    #pragma unroll
    for (int sub = 0; sub < 2; sub++) {
      const int q = sub*4 + quad;
      bf16x8 bf[10];
      #pragma unroll
      for (int n2 = 0; n2 < 10; n2++) {        // B rows 0..9 cover all dh
        const int hp = n2*18 + l15 + dw;
        bf[n2] = *(const bf16x8*)&hB[hp*64 + ((q ^ (hp & 7)) << 3)];
      }
      #pragma unroll
      for (int dh = 0; dh < 3; dh++)
        #pragma unroll
        for (int nt = 0; nt < 8; nt++)
          acc[nt] = __builtin_amdgcn_mfma_f32_16x16x32_bf16(
              cur[dh][sub], bf[nt + dh], acc[nt], 0, 0, 0);
    }
    if (++dw == 3) { dw = 0; cc++; }
  };
  #pragma unroll 1
  for (int uu = 0; uu < 12; uu += 2) {
    body(uu,     afA, afB);
    body(uu + 1, afB, afA);
  }

  const int gx = tx0 + l15;
  if (MODE == 0) {
    const float* __restrict__ bias = br ? bb : bc;
    float* __restrict__ Y = br ? Yb : Yc;
    const int mrow = mtile*64 + wv*16 + quad*4;         // 0..255 global co
    const f32x4 bv = *(const f32x4*)&bias[mrow];
    float s = 0.f, sq = 0.f;
    #pragma unroll
    for (int nt = 0; nt < 8; nt++) {
      const int gy = ty0 + nt;
      f32x4 v = acc[nt] + bv;
      if (gy < W && gx < W) {
        const size_t n = (size_t)(c_off[lv] + gy*W + gx);
        *(f32x4*)&Y[n*CCH + mrow] = v;
        #pragma unroll
        for (int r = 0; r < 4; r++) { s += v[r]; sq += v[r]*v[r]; }
      }
    }
    #pragma unroll
    for (int o = 1; o < 16; o <<= 1) { s += __shfl_xor(s, o); sq += __shfl_xor(sq, o); }
    if (l15 == 0) {
      const int G = mrow >> 3;                 // global 8-ch GN group 0..31
      atomicAdd(&stats[((br*NLEV + lv)*32 + G)*2 + 0], s);
      atomicAdd(&stats[((br*NLEV + lv)*32 + G)*2 + 1], sq);
    }
  } else {
    const float scl = scales[lv];
    const float stf = c_stridef[lv];
    const int mr0 = mtile*64 + wv*16 + quad*4;
    if (mr0 < 85) {
      #pragma unroll
      for (int nt = 0; nt < 8; nt++) {
        const int gy = ty0 + nt;
        if (gy >= W || gx >= W) continue;
        const size_t n = (size_t)(c_off[lv] + gy*W + gx);
        const f32x4 v = acc[nt];
        #pragma unroll
        for (int r = 0; r < 4; r++) {
          const int m = mr0 + r;
          if (br == 0) {
            if (m < 80) out[n*85 + m] = v[r] + bc[m];          // logits
          } else {
            if (m < 4) {
              const float t = (v[r] + predb[m]) * scl;         // Scale module
              out[n*85 + 80 + m] = fmaxf(t, 0.f) * stf;        // relu * stride
            } else if (m == 4) {
              out[n*85 + 84] = v[r] + ioub[0];                 // iou
            }
          }
        }
      }
    }
  }
}

// GN finalize + affine + ReLU + bf16 cast into PLANAR padded layout.
// Y already includes conv bias.
__global__ __launch_bounds__(256) void gn_relu(
    const float* __restrict__ Yc, const float* __restrict__ Yb,
    const float* __restrict__ stats,
    const float* __restrict__ gwc, const float* __restrict__ gbc,
    const float* __restrict__ gwb, const float* __restrict__ gbb,
    u16* __restrict__ Xc, u16* __restrict__ Xb)
{
  const int t = blockIdx.x * 256 + threadIdx.x;
  if (t >= 2 * P_TOT * 32) return;
  const int br = t / (P_TOT * 32);
  const int r  = t - br * (P_TOT * 32);
  const int pg = r >> 5;
  const int c0 = (r & 31) << 3;
  int lv = 0;
  #pragma unroll
  for (int i = 1; i < NLEV; i++) if (pg >= c_off[i]) lv = i;
  const int pl = pg - c_off[lv];
  const int Wl = c_W[lv];
  const int g = c0 >> 3;
  const float* st = &stats[(((size_t)br*NLEV + lv)*32 + g)*2];
  const float cnt = 8.f * (float)c_HW[lv];
  const float mean = st[0] / cnt;
  const float var  = st[1] / cnt - mean*mean;
  const float rstd = rsqrtf(var + 1e-5f);
  const float* Y  = br ? Yb : Yc;
  const float* gw = br ? gwb : gwc;
  const float* gb = br ? gbb : gbc;
  u16* X = br ? Xb : Xc;
  const float* y = &Y[(size_t)pg*CCH + c0];
  const int h = pl / Wl, wi = pl - h*Wl;
  const size_t pidx = (size_t)(c_poff[lv] + (h+1)*(Wl+2) + (wi+1));
  union { u16 u[8]; uint4 v; } pk;
  #pragma unroll
  for (int i = 0; i < 8; i++) {
    const float v = (y[i] - mean)*rstd*gw[c0+i] + gb[c0+i];
    pk.u[i] = f2bf(fmaxf(v, 0.f));
  }
  *(uint4*)&X[(size_t)(c0 >> 6)*PLS + pidx*64 + (c0 & 63)] = pk.v;
}

// fp32 NCHW feats -> bf16 planar padded
__global__ __launch_bounds__(256) void feat2bf(
    const float* __restrict__ p3, const float* __restrict__ p4,
    const float* __restrict__ p5, const float* __restrict__ p6,
    const float* __restrict__ p7, u16* __restrict__ X)
{
  const int t = blockIdx.x * 256 + threadIdx.x;
  if (t >= P_TOT * 32) return;
  const int pg = t >> 5, c0 = (t & 31) << 3;
  int lv = 0;
  #pragma unroll
  for (int i = 1; i < NLEV; i++) if (pg >= c_off[i]) lv = i;
  const int pl = pg - c_off[lv];
  const float* src = lv==0 ? p3 : lv==1 ? p4 : lv==2 ? p5 : lv==3 ? p6 : p7;
  const int HW = c_HW[lv], Wl = c_W[lv];
  const int h = pl / Wl, wi = pl - h*Wl;
  const size_t pidx = (size_t)(c_poff[lv] + (h+1)*(Wl+2) + (wi+1));
  union { u16 u[8]; uint4 v; } pk;
  #pragma unroll
  for (int i = 0; i < 8; i++)
    pk.u[i] = f2bf(src[(size_t)(c0+i)*HW + pl]);
  *(uint4*)&X[(size_t)(c0 >> 6)*PLS + pidx*64 + (c0 & 63)] = pk.v;
}

// tower weights [l][co][ci][9] fp32 -> A-register packed bf16 layout:
// d = l*589824 + s*16384 + (co>>5)*2048 + (kl>>5)*1024 + ((co>>4)&1)*512
//     + ((kl>>3)&3)*128 + (co&15)*8 + (kl&7);  k = tap*256+ci, s=k>>6, kl=k&63.
__global__ __launch_bounds__(256) void wconv(
    const float* __restrict__ cw, const float* __restrict__ bw,
    u16* __restrict__ Wc, u16* __restrict__ Wb)
{
  const size_t N = (size_t)4*256*KTOT;
  const size_t t = (size_t)blockIdx.x * 256 + threadIdx.x;
  if (t >= 2*N) return;
  const float* src = (t < N) ? cw : bw;
  u16* dst = (t < N) ? Wc : Wb;
  const size_t i = (t < N) ? t : t - N;
  const size_t lc = i / KTOT;
  const int kk = (int)(i - lc*KTOT);
  const int l = (int)(lc >> 8), co = (int)(lc & 255);
  const int tap = kk >> 8, ci = kk & 255;
  const int s = kk >> 6, kl = kk & 63;
  const size_t d = (size_t)l*589824 + (size_t)s*16384 +
      (size_t)((co >> 5)*2048 + (kl >> 5)*1024 + ((co >> 4) & 1)*512 +
               ((kl >> 3) & 3)*128 + (co & 15)*8 + (kl & 7));
  dst[d] = f2bf(src[(lc*256 + ci)*9 + tap]);
}

// head weights -> A-register packed (cls: 80 rows; box: 4 pred + 1 iou),
// 128 co rows, per-stage size 8192 u16.
__global__ __launch_bounds__(256) void hconv(
    const float* __restrict__ sw, const float* __restrict__ pw,
    const float* __restrict__ iw, u16* __restrict__ Whc, u16* __restrict__ Whb)
{
  const int N = 128 * KTOT;
  const int t = blockIdx.x * 256 + threadIdx.x;
  if (t >= 2*N) return;
  const int i = (t < N) ? t : t - N;
  const int co = i / KTOT, kk = i - co*KTOT;
  const int tap = kk >> 8, ci = kk & 255;
  const int s = kk >> 6, kl = kk & 63;
  const size_t d = (size_t)s*8192 +
      (size_t)((co >> 5)*2048 + (kl >> 5)*1024 + ((co >> 4) & 1)*512 +
               ((kl >> 3) & 3)*128 + (co & 15)*8 + (kl & 7));
  float v = 0.f;
  if (t < N) {
    if (co < 80) v = sw[(co*256 + ci)*9 + tap];
    Whc[d] = f2bf(v);
  } else {
    if (co < 4)       v = pw[(co*256 + ci)*9 + tap];
    else if (co == 4) v = iw[ci*9 + tap];
    Whb[d] = f2bf(v);
  }
}

extern "C" void kernel_launch(void* const* d_in, const int* in_sizes, int n_in,
                              void* d_out, int out_size, void* d_ws, size_t ws_size,
                              hipStream_t stream)
{
  const float* p3      = (const float*)d_in[0];
  const float* p4      = (const float*)d_in[1];
  const float* p5      = (const float*)d_in[2];
  const float* p6      = (const float*)d_in[3];
  const float* p7      = (const float*)d_in[4];
  const float* cls_w   = (const float*)d_in[5];
  const float* cls_b   = (const float*)d_in[6];
  const float* cls_gw  = (const float*)d_in[7];
  const float* cls_gb  = (const float*)d_in[8];
  const float* box_w   = (const float*)d_in[9];
  const float* box_b   = (const float*)d_in[10];
  const float* box_gw  = (const float*)d_in[11];
  const float* box_gb  = (const float*)d_in[12];
  const float* score_w = (const float*)d_in[13];
  const float* score_b = (const float*)d_in[14];
  const float* pred_w  = (const float*)d_in[15];
  const float* pred_b  = (const float*)d_in[16];
  const float* iou_w   = (const float*)d_in[17];
  const float* iou_b   = (const float*)d_in[18];
  const float* scales  = (const float*)d_in[19];
  float* out = (float*)d_out;

  char* w = (char*)d_ws;
  size_t o = 0;
  auto alloc = [&](size_t b) { void* p = w + o; o += (b + 255) & ~(size_t)255; return p; };
  // X buffers + stats first: zeroed by ONE memset (all 256B multiples)
  u16*   XF = (u16*)alloc((size_t)PP_TOT*CCH*2);   // planar [4][PP_TOT][64]
  u16*   XC = (u16*)alloc((size_t)PP_TOT*CCH*2);
  u16*   XB = (u16*)alloc((size_t)PP_TOT*CCH*2);
  float* ST = (float*)alloc((size_t)4*2*NLEV*32*2*4);   // [layer][br][lv][32][2]
  u16*  WRC = (u16*)alloc((size_t)4*256*KTOT*2);
  u16*  WRB = (u16*)alloc((size_t)4*256*KTOT*2);
  u16*  WHC = (u16*)alloc((size_t)128*KTOT*2);
  u16*  WHB = (u16*)alloc((size_t)128*KTOT*2);
  float* YC = (float*)alloc((size_t)P_TOT*CCH*4);
  float* YB = (float*)alloc((size_t)P_TOT*CCH*4);

  // zero padded activation borders + all layers' GN stats in one shot
  hipMemsetAsync(XF, 0, (size_t)3*PP_TOT*CCH*2 + (size_t)4*2*NLEV*32*2*4, stream);

  wconv<<<dim3((unsigned)(((size_t)2*4*256*KTOT + 255)/256)), 256, 0, stream>>>(cls_w, box_w, WRC, WRB);
  hconv<<<dim3((2*128*KTOT + 255)/256), 256, 0, stream>>>(score_w, pred_w, iou_w, WHC, WHB);
  feat2bf<<<dim3((P_TOT*32 + 255)/256), 256, 0, stream>>>(p3, p4, p5, p6, p7, XF);

  const u16* xci = XF; const u16* xbi = XF;
  for (int l = 0; l < 4; l++) {
    float* STl = ST + (size_t)l*2*NLEV*32*2;
    gemm_conv<0><<<dim3(74, 4, 2), 256, 0, stream>>>(
        xci, xbi, WRC + (size_t)l*589824, WRB + (size_t)l*589824,
        cls_b + l*256, box_b + l*256, YC, YB, STl,
        nullptr, nullptr, nullptr, nullptr);
    gn_relu<<<dim3((2*P_TOT*32 + 255)/256), 256, 0, stream>>>(
        YC, YB, STl, cls_gw + l*256, cls_gb + l*256, box_gw + l*256, box_gb + l*256,
        XC, XB);
    xci = XC; xbi = XB;
  }
  gemm_conv<1><<<dim3(74, 3, 1), 256, 0, stream>>>(
      xci, xbi, WHC, WHB, score_b, nullptr, nullptr, nullptr, nullptr,
      pred_b, iou_b, scales, out);
}